// Round 2
// baseline (1475.214 us; speedup 1.0000x reference)
//
#include <hip/hip_runtime.h>
#include <stdint.h>

// BMM_S8T_S8N_F32T: out[b,m,n] = alpha * sum_k a[b,m,k]*b[b,n,k]
// B=64, M=N=2048, K=64. Harness delivers integer inputs as int32
// ("integer -> const int*"), values in [-128,127]; we pack to i8
// in-register. fp32 output.
//
// Roofline: output writes (1.07 GB fp32) dominate (~170 us at 6.3 TB/s).
// One mfma_i32_16x16x64_i8 consumes the full K per 16x16 tile.
// Block = 4 waves, 64x64 output tile; wave computes 16(m) x 64(n),
// reusing its A fragment across 4 B fragments. No LDS.

#define MM 2048
#define NN 2048
#define KK 64

typedef int v4i __attribute__((ext_vector_type(4)));

static __device__ inline int pack4(int b0, int b1, int b2, int b3) {
    return (int)((unsigned)(b0 & 0xFF)        |
                 ((unsigned)(b1 & 0xFF) << 8) |
                 ((unsigned)(b2 & 0xFF) << 16)|
                 ((unsigned)(b3 & 0xFF) << 24));
}

// Load 16 consecutive int32 (each in [-128,127]) and pack to 16 bytes.
static __device__ inline v4i load_pack16(const int* __restrict__ p) {
    v4i w0 = *(const v4i*)(p + 0);
    v4i w1 = *(const v4i*)(p + 4);
    v4i w2 = *(const v4i*)(p + 8);
    v4i w3 = *(const v4i*)(p + 12);
    v4i r;
    r.x = pack4(w0.x, w0.y, w0.z, w0.w);
    r.y = pack4(w1.x, w1.y, w1.z, w1.w);
    r.z = pack4(w2.x, w2.y, w2.z, w2.w);
    r.w = pack4(w3.x, w3.y, w3.z, w3.w);
    return r;
}

__global__ __launch_bounds__(256) void bmm_s8t_s8n_f32t_kernel(
    const int* __restrict__ A,
    const int* __restrict__ Bm,
    const float* __restrict__ alpha_p,
    float* __restrict__ Out)
{
    const int wave   = threadIdx.x >> 6;
    const int lane   = threadIdx.x & 63;
    const int lane16 = lane & 15;
    const int lanehi = lane >> 4;

    const int batch  = blockIdx.z;
    const int m_base = blockIdx.y * 64 + wave * 16;
    const int n_base = blockIdx.x * 64;

    const float alpha = *alpha_p;

    const int* a_ptr = A  + ((size_t)batch * MM + m_base) * KK;
    const int* b_ptr = Bm + ((size_t)batch * NN + n_base) * KK;

    // A fragment: lane holds A[m = lane16][k = lanehi*16 + 0..15]
    v4i a_frag = load_pack16(a_ptr + lane16 * KK + lanehi * 16);

    // Four B fragments: n-tiles at n_base + {0,16,32,48}
    v4i b0 = load_pack16(b_ptr + ( 0 + lane16) * KK + lanehi * 16);
    v4i b1 = load_pack16(b_ptr + (16 + lane16) * KK + lanehi * 16);
    v4i b2 = load_pack16(b_ptr + (32 + lane16) * KK + lanehi * 16);
    v4i b3 = load_pack16(b_ptr + (48 + lane16) * KK + lanehi * 16);

    v4i zero = {0, 0, 0, 0};
    v4i acc0 = __builtin_amdgcn_mfma_i32_16x16x64_i8(a_frag, b0, zero, 0, 0, 0);
    v4i acc1 = __builtin_amdgcn_mfma_i32_16x16x64_i8(a_frag, b1, zero, 0, 0, 0);
    v4i acc2 = __builtin_amdgcn_mfma_i32_16x16x64_i8(a_frag, b2, zero, 0, 0, 0);
    v4i acc3 = __builtin_amdgcn_mfma_i32_16x16x64_i8(a_frag, b3, zero, 0, 0, 0);

    // C/D layout (16x16, dtype-independent): m = lanehi*4 + reg, n = lane16.
    // For fixed reg, 16 consecutive lanes write 64B contiguous aligned.
    float* o_ptr = Out + ((size_t)batch * MM + m_base) * (size_t)NN + n_base;
#pragma unroll
    for (int r = 0; r < 4; ++r) {
        const size_t row_off = (size_t)(lanehi * 4 + r) * NN;
        o_ptr[row_off +  0 + lane16] = alpha * (float)acc0[r];
        o_ptr[row_off + 16 + lane16] = alpha * (float)acc1[r];
        o_ptr[row_off + 32 + lane16] = alpha * (float)acc2[r];
        o_ptr[row_off + 48 + lane16] = alpha * (float)acc3[r];
    }
}

extern "C" void kernel_launch(void* const* d_in, const int* in_sizes, int n_in,
                              void* d_out, int out_size, void* d_ws, size_t ws_size,
                              hipStream_t stream) {
    const int*   a     = (const int*)d_in[0];    // (64, 2048, 64) int32 (values fit int8)
    const int*   b     = (const int*)d_in[1];    // (64, 2048, 64) int32
    const float* alpha = (const float*)d_in[2];  // scalar fp32
    float*       out   = (float*)d_out;          // (64, 2048, 2048) fp32

    dim3 grid(NN / 64, MM / 64, 64);  // (n-tiles, m-tiles, batch)
    dim3 block(256);
    bmm_s8t_s8n_f32t_kernel<<<grid, block, 0, stream>>>(a, b, alpha, out);
}